// Round 2
// baseline (85.584 us; speedup 1.0000x reference)
//
#include <hip/hip_runtime.h>

// Encoder: out[p, 0:300]   = batch[p] < 20000 ? vectors[batch[p], :] : 0
//          out[p, 300:556] = b[:] + (batch[p] >= 20000 ? W[:, batch[p]-20000] : 0)
// Pure gather — the one-hot einsum selects a single column of W. No matmul.
// All fp tensors are float32 per the reference (R1 NaN post-mortem: bf16
// misread of fp32 data produced NaN patterns).

#define N_PRE 20000
#define VEC_DIM 300
#define INPUT_SIZE 10000
#define HIDDEN 256
#define OUT_DIM (VEC_DIM + HIDDEN)  // 556

__global__ __launch_bounds__(256) void encoder_gather_kernel(
    const int* __restrict__ batch,      // [n_tokens]
    const float* __restrict__ vectors,  // [20000, 300]
    const float* __restrict__ W,        // [256, 10000] row-major
    const float* __restrict__ b,        // [256]
    float* __restrict__ out,            // [n_tokens, 556]
    int n_tokens)
{
    const int p = blockIdx.x;
    if (p >= n_tokens) return;
    const int t = batch[p];

    float* orow = out + (size_t)p * OUT_DIM;

    // --- x1: embedding gather (coalesced contiguous 300-float row) ---
    if (t < N_PRE) {
        const float* vrow = vectors + (size_t)t * VEC_DIM;
        for (int j = threadIdx.x; j < VEC_DIM; j += blockDim.x) {
            orow[j] = vrow[j];
        }
    } else {
        for (int j = threadIdx.x; j < VEC_DIM; j += blockDim.x) {
            orow[j] = 0.0f;
        }
    }

    // --- x2: one column of W (strided gather, L2/L3-resident) + bias ---
    const int h = threadIdx.x;
    if (h < HIDDEN) {
        float acc = b[h];
        if (t >= N_PRE) {
            acc += W[(size_t)h * INPUT_SIZE + (t - N_PRE)];
        }
        orow[VEC_DIM + h] = acc;
    }
}

extern "C" void kernel_launch(void* const* d_in, const int* in_sizes, int n_in,
                              void* d_out, int out_size, void* d_ws, size_t ws_size,
                              hipStream_t stream) {
    const int* batch     = (const int*)d_in[0];
    const float* vectors = (const float*)d_in[1];
    const float* W       = (const float*)d_in[2];
    const float* b       = (const float*)d_in[3];
    float* out           = (float*)d_out;

    const int n_tokens = in_sizes[0];  // 8 * 512 = 4096

    encoder_gather_kernel<<<n_tokens, 256, 0, stream>>>(
        batch, vectors, W, b, out, n_tokens);
}